// Round 4
// baseline (454.252 us; speedup 1.0000x reference)
//
#include <hip/hip_runtime.h>
#include <hip/hip_bf16.h>

typedef __attribute__((ext_vector_type(8))) short short8;
typedef __attribute__((ext_vector_type(4))) float f32x4;

#define GLD16(gp, lp) \
  __builtin_amdgcn_global_load_lds((const __attribute__((address_space(1))) void*)(gp), \
                                   (__attribute__((address_space(3))) void*)(lp), 16, 0, 0)

__device__ __forceinline__ f32x4 mfma_bf16(short8 a, short8 b, f32x4 c) {
  return __builtin_amdgcn_mfma_f32_16x16x32_bf16(a, b, c, 0, 0, 0);
}

// ---------------- prep: cast x/qkv_w/proj_w to bf16 + RoPE table, one kernel ----------------
__global__ __launch_bounds__(256) void prep_kernel(
    const float* __restrict__ x, const float* __restrict__ w1,
    const float* __restrict__ w2, __hip_bfloat16* __restrict__ xb,
    __hip_bfloat16* __restrict__ w1b, __hip_bfloat16* __restrict__ w2b,
    float* __restrict__ cosT, float* __restrict__ sinT) {
  const int N1 = 4816896;            // 25088*768/4
  const int N2 = N1 + 442368;        // + 2304*768/4
  const int N3 = N2 + 147456;        // + 768*768/4  (= 5406720 = 21120*256)
  int i = blockIdx.x * 256 + threadIdx.x;
  if (i < N3) {
    const float* src;
    __hip_bfloat16* dst;
    int j;
    if (i < N1) { src = x; dst = xb; j = i; }
    else if (i < N2) { src = w1; dst = w1b; j = i - N1; }
    else { src = w2; dst = w2b; j = i - N2; }
    float4 v = reinterpret_cast<const float4*>(src)[j];
    ushort4 o;
    o.x = __builtin_bit_cast(unsigned short, __float2bfloat16(v.x));
    o.y = __builtin_bit_cast(unsigned short, __float2bfloat16(v.y));
    o.z = __builtin_bit_cast(unsigned short, __float2bfloat16(v.z));
    o.w = __builtin_bit_cast(unsigned short, __float2bfloat16(v.w));
    reinterpret_cast<ushort4*>(dst)[j] = o;
  } else {
    int r = i - N3;                  // rope table: 196*64 = 12544 entries
    if (r < 196 * 64) {
      int t = r >> 6, d = r & 63;
      int c = d & 31;
      float pos = (c < 16) ? (float)(t / 14) : (float)(t % 14);
      int jj = c & 15;
      float invf = expf(-(float)jj * 0.5756462732485114f);  // 10000^(-j/16)
      float ang = pos * invf;
      cosT[r] = cosf(ang);
      sinT[r] = sinf(ang);
    }
  }
}

// ---------------- QKV GEMM: [25088x768] x [2304x768]^T + bias, fused RoPE,
//                  scatter to q/k/v [128][12][196][64] bf16 ----------------
// Tile 128Mx256N, BK=64: 9 bn-passes over A (halved from 18 -> fetch cut),
// 64 MFMA per barrier drain. XOR chunk-swizzle keeps ds_read_b128 conflict-free.
__global__ __launch_bounds__(256) void gemm_qkv_kernel(
    const __hip_bfloat16* __restrict__ A, const __hip_bfloat16* __restrict__ W,
    const float* __restrict__ bias, const float* __restrict__ cosT,
    const float* __restrict__ sinT, __hip_bfloat16* __restrict__ qb,
    __hip_bfloat16* __restrict__ kb, __hip_bfloat16* __restrict__ vb) {
  __shared__ __align__(16) __hip_bfloat16 As[128 * 64];
  __shared__ __align__(16) __hip_bfloat16 Bs[256 * 64];
  const int tid = threadIdx.x;
  const int id = blockIdx.x;
  const int bm = id / 9, bn = id % 9;       // bm-major: 9 consecutive ids share A-tile
  const int lane = tid & 63, wv = tid >> 6;
  const int wm = wv >> 1, wn = wv & 1;      // wave = 64M x 128N
  const int quad = lane >> 4, ln = lane & 15;

  const int r0 = tid >> 3;
  const int csw = ((tid & 7) ^ (r0 & 7)) * 8;
  const __hip_bfloat16* Ag = A + ((long)(bm * 128 + r0) * 768 + csw);
  const __hip_bfloat16* Wg = W + ((long)(bn * 256 + r0) * 768 + csw);
  __hip_bfloat16* As0 = As + tid * 8;
  __hip_bfloat16* Bs0 = Bs + tid * 8;

  const int c0 = (quad ^ (ln & 7)) * 8;
  const int c1 = c0 ^ 32;

  f32x4 acc[4][8];
#pragma unroll
  for (int i = 0; i < 4; i++)
#pragma unroll
    for (int j = 0; j < 8; j++) acc[i][j] = (f32x4){0.f, 0.f, 0.f, 0.f};

  for (int k0 = 0; k0 < 768; k0 += 64) {
#pragma unroll
    for (int b = 0; b < 4; b++) GLD16(Ag + (long)b * 32 * 768 + k0, As0 + b * 2048);
#pragma unroll
    for (int b = 0; b < 8; b++) GLD16(Wg + (long)b * 32 * 768 + k0, Bs0 + b * 2048);
    __syncthreads();
#pragma unroll
    for (int kk = 0; kk < 2; kk++) {
      const int cc = kk ? c1 : c0;
      short8 af[4], bf[8];
#pragma unroll
      for (int i = 0; i < 4; i++)
        af[i] = *(const short8*)(As + (wm * 64 + i * 16 + ln) * 64 + cc);
#pragma unroll
      for (int j = 0; j < 8; j++)
        bf[j] = *(const short8*)(Bs + (wn * 128 + j * 16 + ln) * 64 + cc);
#pragma unroll
      for (int i = 0; i < 4; i++)
#pragma unroll
        for (int j = 0; j < 8; j++) acc[i][j] = mfma_bf16(af[i], bf[j], acc[i][j]);
    }
    __syncthreads();
  }

  // Epilogue: wave spans 128 N-cols = 2 heads of one s (256 | 768 so bn-tile
  // is within one of q/k/v). RoPE pairs are (j, j^2) lane-local.
  const int ncb = bn * 256 + wn * 128;
  const int s = ncb / 768;                  // 0=q 1=k 2=v (wave-uniform)
  const int h0 = (ncb % 768) >> 6;          // first head of the wave's span
  __hip_bfloat16* outb = (s == 0) ? qb : ((s == 1) ? kb : vb);
  float bi[8];
#pragma unroll
  for (int j = 0; j < 8; j++) bi[j] = bias[ncb + j * 16 + ln];
  const bool dorope = (s < 2);

#pragma unroll
  for (int i = 0; i < 4; i++) {
#pragma unroll
    for (int r = 0; r < 4; r++) {
      int m = bm * 128 + wm * 64 + i * 16 + quad * 4 + r;  // C layout: row = quad*4+reg
      int b = m / 196, t = m - b * 196;
      float v[8];
#pragma unroll
      for (int j = 0; j < 8; j++) v[j] = acc[i][j][r] + bi[j];
      if (dorope) {
        const float* ct = cosT + t * 64 + ln;
        const float* st = sinT + t * 64 + ln;
        float cv[4], sv[4];
#pragma unroll
        for (int u = 0; u < 4; u++) { cv[u] = ct[u * 16]; sv[u] = st[u * 16]; }
#pragma unroll
        for (int p = 0; p < 4; p++) {          // pairs (0,2)(1,3)(4,6)(5,7)
          int jl = (p & 1) + (p & 2) * 2;      // 0,1,4,5
          int jh = jl + 2;
          int dl = jl & 3, dh = dl + 2;        // cos/sin slots
          float lo = v[jl] * cv[dl] - v[jh] * sv[dl];
          float hi = v[jh] * cv[dh] + v[jl] * sv[dh];
          v[jl] = lo; v[jh] = hi;
        }
      }
      __hip_bfloat16* op0 = outb + ((long)(b * 12 + h0) * 196 + t) * 64 + ln;
      __hip_bfloat16* op1 = op0 + 196 * 64;
#pragma unroll
      for (int j = 0; j < 4; j++) op0[j * 16] = __float2bfloat16(v[j]);
#pragma unroll
      for (int j = 0; j < 4; j++) op1[j * 16] = __float2bfloat16(v[4 + j]);
    }
  }
}

// ---------------- attention: one block per (b,h), 4 waves ----------------
__global__ __launch_bounds__(256) void attn_kernel(
    const __hip_bfloat16* __restrict__ qb, const __hip_bfloat16* __restrict__ kb,
    const __hip_bfloat16* __restrict__ vb, __hip_bfloat16* __restrict__ att) {
  __shared__ __align__(16) __hip_bfloat16 Vt[64 * 232];      // V^T [d][key], keys padded to 224
  __shared__ __align__(16) __hip_bfloat16 Ps[4][16 * 232];   // per-wave P tile
  const int bh = blockIdx.x;
  const int b = bh / 12, h = bh - b * 12;
  const int tid = threadIdx.x;
  const int lane = tid & 63, wv = tid >> 6;
  const int quad = lane >> 4, ln = lane & 15;
  const __hip_bfloat16* qg = qb + (long)bh * (196 * 64);
  const __hip_bfloat16* kg = kb + (long)bh * (196 * 64);
  const __hip_bfloat16* vg = vb + (long)bh * (196 * 64);

  // stage V transposed (zero-pad keys 196..223)
  for (int ch = tid; ch < 224 * 8; ch += 256) {
    int row = ch >> 3, c = (ch & 7) * 8;
    unsigned short vals[8] = {0, 0, 0, 0, 0, 0, 0, 0};
    if (row < 196) *(uint4*)vals = *(const uint4*)(vg + row * 64 + c);
#pragma unroll
    for (int u = 0; u < 8; u++)
      ((unsigned short*)Vt)[(c + u) * 232 + row] = vals[u];
  }

  __hip_bfloat16* Pw = &Ps[wv][0];
#pragma unroll
  for (int r = 0; r < 4; r++)            // zero pad cols 208..223 once
    Pw[(quad * 4 + r) * 232 + 208 + ln] = __float2bfloat16(0.f);
  __syncthreads();

  for (int qt = wv; qt < 13; qt += 4) {
    int tok = qt * 16 + ln;
    if (tok > 195) tok = 195;            // clamped rows masked at store
    short8 aq0 = *(const short8*)(qg + tok * 64 + quad * 8);
    short8 aq1 = *(const short8*)(qg + tok * 64 + 32 + quad * 8);

    f32x4 sacc[13];
#pragma unroll
    for (int ct = 0; ct < 13; ct++) {
      int krow = ct * 16 + ln;
      if (krow > 195) krow = 195;        // garbage cols zeroed below
      const __hip_bfloat16* kp = kg + krow * 64 + quad * 8;
      short8 b0 = *(const short8*)kp;
      short8 b1 = *(const short8*)(kp + 32);
      f32x4 cacc = (f32x4){0.f, 0.f, 0.f, 0.f};
      cacc = mfma_bf16(aq0, b0, cacc);
      cacc = mfma_bf16(aq1, b1, cacc);
      sacc[ct] = cacc;
    }

    // no-max softmax: p = exp(s/8), invalid cols -> 0
    float sm[4] = {0.f, 0.f, 0.f, 0.f};
#pragma unroll
    for (int ct = 0; ct < 13; ct++) {
      bool valid = (ct * 16 + ln) < 196;
#pragma unroll
      for (int r = 0; r < 4; r++) {
        float p = valid ? __expf(sacc[ct][r] * 0.125f) : 0.f;
        sm[r] += p;
        Pw[(quad * 4 + r) * 232 + ct * 16 + ln] = __float2bfloat16(p);
      }
    }
#pragma unroll
    for (int mk = 1; mk < 16; mk <<= 1) {
#pragma unroll
      for (int r = 0; r < 4; r++) sm[r] += __shfl_xor(sm[r], mk, 64);
    }
    asm volatile("" ::: "memory");  // order P stores vs short8 reloads (TBAA guard)

    f32x4 o[4];
#pragma unroll
    for (int j = 0; j < 4; j++) o[j] = (f32x4){0.f, 0.f, 0.f, 0.f};
#pragma unroll
    for (int kt = 0; kt < 7; kt++) {
      short8 pa = *(const short8*)(Pw + ln * 232 + kt * 32 + quad * 8);
#pragma unroll
      for (int j = 0; j < 4; j++) {
        short8 bv = *(const short8*)(Vt + (j * 16 + ln) * 232 + kt * 32 + quad * 8);
        o[j] = mfma_bf16(pa, bv, o[j]);
      }
    }
    asm volatile("" ::: "memory");

    float rl[4];
#pragma unroll
    for (int r = 0; r < 4; r++) rl[r] = 1.0f / sm[r];
    int trow = qt * 16 + quad * 4;
#pragma unroll
    for (int r = 0; r < 4; r++) {
      int t = trow + r;
      if (t < 196) {
        __hip_bfloat16* op = att + (long)(b * 196 + t) * 768 + h * 64 + ln;
#pragma unroll
        for (int j = 0; j < 4; j++) op[j * 16] = __float2bfloat16(o[j][r] * rl[r]);
      }
    }
  }
}

// ---------------- proj GEMM: [25088x768] x [768x768]^T + bias -> fp32 out ----------------
// Tile 128Mx256N, BK=64: 3 bn-passes over A. XOR chunk-swizzle.
__global__ __launch_bounds__(256) void gemm_proj_kernel(
    const __hip_bfloat16* __restrict__ A, const __hip_bfloat16* __restrict__ W,
    const float* __restrict__ bias, float* __restrict__ out) {
  __shared__ __align__(16) __hip_bfloat16 As[128 * 64];
  __shared__ __align__(16) __hip_bfloat16 Bs[256 * 64];
  const int tid = threadIdx.x;
  const int id = blockIdx.x;
  const int bm = id / 3, bn = id % 3;
  const int lane = tid & 63, wv = tid >> 6;
  const int wm = wv >> 1, wn = wv & 1;
  const int quad = lane >> 4, ln = lane & 15;

  const int r0 = tid >> 3;
  const int csw = ((tid & 7) ^ (r0 & 7)) * 8;
  const __hip_bfloat16* Ag = A + ((long)(bm * 128 + r0) * 768 + csw);
  const __hip_bfloat16* Wg = W + ((long)(bn * 256 + r0) * 768 + csw);
  __hip_bfloat16* As0 = As + tid * 8;
  __hip_bfloat16* Bs0 = Bs + tid * 8;

  const int c0 = (quad ^ (ln & 7)) * 8;
  const int c1 = c0 ^ 32;

  f32x4 acc[4][8];
#pragma unroll
  for (int i = 0; i < 4; i++)
#pragma unroll
    for (int j = 0; j < 8; j++) acc[i][j] = (f32x4){0.f, 0.f, 0.f, 0.f};

  for (int k0 = 0; k0 < 768; k0 += 64) {
#pragma unroll
    for (int b = 0; b < 4; b++) GLD16(Ag + (long)b * 32 * 768 + k0, As0 + b * 2048);
#pragma unroll
    for (int b = 0; b < 8; b++) GLD16(Wg + (long)b * 32 * 768 + k0, Bs0 + b * 2048);
    __syncthreads();
#pragma unroll
    for (int kk = 0; kk < 2; kk++) {
      const int cc = kk ? c1 : c0;
      short8 af[4], bf[8];
#pragma unroll
      for (int i = 0; i < 4; i++)
        af[i] = *(const short8*)(As + (wm * 64 + i * 16 + ln) * 64 + cc);
#pragma unroll
      for (int j = 0; j < 8; j++)
        bf[j] = *(const short8*)(Bs + (wn * 128 + j * 16 + ln) * 64 + cc);
#pragma unroll
      for (int i = 0; i < 4; i++)
#pragma unroll
        for (int j = 0; j < 8; j++) acc[i][j] = mfma_bf16(af[i], bf[j], acc[i][j]);
    }
    __syncthreads();
  }

  const int ncb = bn * 256 + wn * 128;
  float bi[8];
#pragma unroll
  for (int j = 0; j < 8; j++) bi[j] = bias[ncb + j * 16 + ln];
#pragma unroll
  for (int i = 0; i < 4; i++) {
#pragma unroll
    for (int r = 0; r < 4; r++) {
      int m = bm * 128 + wm * 64 + i * 16 + quad * 4 + r;
      float* op = out + (long)m * 768 + ncb + ln;
#pragma unroll
      for (int j = 0; j < 8; j++) op[j * 16] = acc[i][j][r] + bi[j];
    }
  }
}

extern "C" void kernel_launch(void* const* d_in, const int* in_sizes, int n_in,
                              void* d_out, int out_size, void* d_ws, size_t ws_size,
                              hipStream_t stream) {
  const float* x      = (const float*)d_in[0];
  const float* qkv_w  = (const float*)d_in[1];
  const float* qkv_b  = (const float*)d_in[2];
  const float* proj_w = (const float*)d_in[3];
  const float* proj_b = (const float*)d_in[4];
  float* out = (float*)d_out;
  (void)in_sizes; (void)n_in; (void)out_size; (void)ws_size;

  char* ws = (char*)d_ws;
  size_t off = 0;
  auto alloc = [&](size_t bytes) -> void* {
    void* p = (void*)(ws + off);
    off += (bytes + 255) & ~(size_t)255;
    return p;
  };
  const size_t MB0 = (size_t)25088 * 768 * 2;  // 38,535,168 B
  __hip_bfloat16* xb   = (__hip_bfloat16*)alloc(MB0);
  __hip_bfloat16* w1b  = (__hip_bfloat16*)alloc((size_t)2304 * 768 * 2);
  __hip_bfloat16* w2b  = (__hip_bfloat16*)alloc((size_t)768 * 768 * 2);
  float* cosT          = (float*)alloc(196 * 64 * 4);
  float* sinT          = (float*)alloc(196 * 64 * 4);
  __hip_bfloat16* qbuf = (__hip_bfloat16*)alloc(MB0);
  __hip_bfloat16* kbuf = (__hip_bfloat16*)alloc(MB0);
  __hip_bfloat16* vbuf = (__hip_bfloat16*)alloc(MB0);
  __hip_bfloat16* attb = xb;  // alias: xb dead after gemm_qkv

  prep_kernel<<<21169, 256, 0, stream>>>(x, qkv_w, proj_w, xb, w1b, w2b, cosT, sinT);
  gemm_qkv_kernel<<<1764, 256, 0, stream>>>(xb, w1b, qkv_b, cosT, sinT,
                                            qbuf, kbuf, vbuf);
  attn_kernel<<<1536, 256, 0, stream>>>(qbuf, kbuf, vbuf, attb);
  gemm_proj_kernel<<<588, 256, 0, stream>>>(attb, w2b, proj_b, out);
}